// Round 1
// baseline (6108.058 us; speedup 1.0000x reference)
//
#include <hip/hip_runtime.h>
#include <hip/hip_bf16.h>

// QLSTM: SEQ=1024, B=64, D_IN=256, D_H=256, fp32 in/out.
// Phase 1: Xp = x @ Wx + bias  (f16 MFMA GEMM, no sequential dep)
// Phase 2: 64 independent recurrences (1 WG per batch element),
//          Wh in VGPRs(448)+LDS(64KB), v_dot2_f32_f16 inner product.

typedef _Float16 f16;
typedef _Float16 f16x2 __attribute__((ext_vector_type(2)));
typedef _Float16 f16x4 __attribute__((ext_vector_type(4)));
typedef _Float16 f16x8 __attribute__((ext_vector_type(8)));
typedef float f32x4 __attribute__((ext_vector_type(4)));

#define SEQ 1024
#define BATCH 64
#define DIN 256
#define DH 256
#define NCOL 1024          // 4 gates * 256
#define KR 224             // recurrent K rows kept in VGPRs (rest: 32 rows in LDS)

// ---- ws layout (bytes) ----
#define WXP_OFF   0u                 // f16 [32][1024][8]  (Wx packed for MFMA B staging)
#define WHR_OFF   524288u            // f16 [1024][224]    (Wh rows 0..223, col-major per col)
#define WHL_OFF   983040u            // f16 [4][1024][8]   (Wh rows 224..255)
#define BIAS_OFF  1048576u           // f32 [1024] gate-major
#define HXS_OFF   1052672u           // f16 [64][256]  hx state between chunks
#define CXS_OFF   1085440u           // f32 [64][256]  cx state between chunks
#define XP_OFF    1150976u           // f16 [Tc*64][1024]

__device__ __forceinline__ float dot2(unsigned int h, unsigned int w, float acc) {
#if __has_builtin(__builtin_amdgcn_fdot2)
  return __builtin_amdgcn_fdot2(__builtin_bit_cast(f16x2, h),
                                __builtin_bit_cast(f16x2, w), acc, false);
#else
  f16x2 a = __builtin_bit_cast(f16x2, h);
  f16x2 b = __builtin_bit_cast(f16x2, w);
  return acc + (float)a[0] * (float)b[0] + (float)a[1] * (float)b[1];
#endif
}

__device__ __forceinline__ float fast_sigmoid(float x) {
  float e = __expf(-x);
  return __builtin_amdgcn_rcpf(1.0f + e);
}
__device__ __forceinline__ float fast_tanh(float x) {
  x = fminf(fmaxf(x, -15.0f), 15.0f);
  float e = __expf(2.0f * x);
  return (e - 1.0f) * __builtin_amdgcn_rcpf(e + 1.0f);
}

// ---------------- prep: convert / repack weights ----------------
__global__ void qlstm_prep(const float* __restrict__ Wf, const float* __restrict__ Wi,
                           const float* __restrict__ Wg, const float* __restrict__ Wo,
                           const float* __restrict__ bf_, const float* __restrict__ bi_,
                           const float* __restrict__ bg_, const float* __restrict__ bo_,
                           f16* __restrict__ Wxp, f16* __restrict__ Whr,
                           f16* __restrict__ Whl, float* __restrict__ biasp) {
  int tid = blockIdx.x * 256 + threadIdx.x;     // 4*512*256 = 524288 total
  if (tid < 4 * 512 * 256) {
    int g = tid >> 17;
    int rem = tid & 131071;
    int k = rem >> 8, n = rem & 255;
    const float* W = (g == 0) ? Wf : (g == 1) ? Wi : (g == 2) ? Wg : Wo;
    float v = W[k * 256 + n];
    int j = (g << 8) + n;
    f16 hv = (f16)v;
    if (k < 256) {
      Wxp[((size_t)(k >> 3) * 1024 + j) * 8 + (k & 7)] = hv;
    } else {
      int kk = k - 256;
      if (kk < KR) {
        Whr[(size_t)j * KR + kk] = hv;
      } else {
        int c = (kk - KR) >> 3;
        Whl[((size_t)c * 1024 + j) * 8 + ((kk - KR) & 7)] = hv;
      }
    }
  }
  if (tid < 1024) {
    int g = tid >> 8, n = tid & 255;
    const float* bb = (g == 0) ? bf_ : (g == 1) ? bi_ : (g == 2) ? bg_ : bo_;
    biasp[tid] = bb[n];
  }
}

// ---------------- phase 1: Xp = x @ Wx + bias  (MFMA f16) ----------------
// tile 128(M) x 128(N), BK=64, 256 threads (4 waves, each 64x64 quadrant)
__global__ __launch_bounds__(256) void qlstm_xproj(
    const float* __restrict__ X,       // [M][256] fp32 (rows = t*64+b within chunk)
    const f16* __restrict__ Wxp,       // [32][1024][8]
    const float* __restrict__ biasp,   // [1024]
    f16* __restrict__ Xp) {            // [M][1024] f16
  __shared__ f16 As[128][72];          // pitch 72 f16 = 144B (16B aligned rows)
  __shared__ f16 Bs[8 * 128 * 8];      // [kgi][n][e]

  int tid = threadIdx.x;
  int tm = blockIdx.x, tn = blockIdx.y;
  int wave = tid >> 6, lane = tid & 63;
  int qm = (wave & 1) * 64, qn = (wave >> 1) * 64;
  int lm = lane & 15, lk = lane >> 4;

  f32x4 acc[4][4];
#pragma unroll
  for (int a = 0; a < 4; ++a)
#pragma unroll
    for (int b = 0; b < 4; ++b) acc[a][b] = (f32x4)0.0f;

  for (int k0 = 0; k0 < 256; k0 += 64) {
    // stage A: 128 rows x 64 k fp32 -> f16
    {
      int r = tid >> 1, c0 = (tid & 1) * 32;
      const float4* src = (const float4*)(X + (size_t)(tm * 128 + r) * 256 + k0 + c0);
#pragma unroll
      for (int i = 0; i < 8; ++i) {
        float4 v = src[i];
        f16x4 pk = {(f16)v.x, (f16)v.y, (f16)v.z, (f16)v.w};
        *(f16x4*)&As[r][c0 + i * 4] = pk;
      }
    }
    // stage B: 8 kg-blocks x 128 cols x 8  (straight 16B copy)
    {
#pragma unroll
      for (int it = 0; it < 4; ++it) {
        int idx = it * 256 + tid;               // 0..1023
        int kgi = idx >> 7, n = idx & 127;
        ((uint4*)Bs)[idx] =
            *(const uint4*)(Wxp + (((size_t)(k0 >> 3) + kgi) * 1024 + tn * 128 + n) * 8);
      }
    }
    __syncthreads();
#pragma unroll
    for (int ks = 0; ks < 2; ++ks) {
      f16x8 af[4], bfr[4];
#pragma unroll
      for (int mi = 0; mi < 4; ++mi)
        af[mi] = *(const f16x8*)&As[qm + mi * 16 + lm][ks * 32 + lk * 8];
#pragma unroll
      for (int ni = 0; ni < 4; ++ni)
        bfr[ni] = *(const f16x8*)&Bs[(((ks * 4 + lk) * 128) + qn + ni * 16 + lm) * 8];
#pragma unroll
      for (int mi = 0; mi < 4; ++mi)
#pragma unroll
        for (int ni = 0; ni < 4; ++ni)
          acc[mi][ni] = __builtin_amdgcn_mfma_f32_16x16x32_f16(af[mi], bfr[ni],
                                                               acc[mi][ni], 0, 0, 0);
    }
    __syncthreads();
  }
  // epilogue: C layout col=lane&15, row=(lane>>4)*4+reg
  int m0 = tm * 128 + qm, j0 = tn * 128 + qn;
#pragma unroll
  for (int mi = 0; mi < 4; ++mi)
#pragma unroll
    for (int ni = 0; ni < 4; ++ni) {
      int j = j0 + ni * 16 + lm;
      float bv = biasp[j];
#pragma unroll
      for (int r = 0; r < 4; ++r) {
        int m = m0 + mi * 16 + lk * 4 + r;
        Xp[(size_t)m * 1024 + j] = (f16)(acc[mi][ni][r] + bv);
      }
    }
}

// ---------------- phase 2: sequential LSTM, 1 WG per batch element ----------------
// 256 threads; thread h owns gate-columns {h, 256+h, 512+h, 768+h}; cx in register.
// Wh rows 0..223 in VGPRs (4 cols * 28 uint4 = 448 VGPR), rows 224..255 in LDS.
__global__ __launch_bounds__(256, 1) void qlstm_seq(
    const f16* __restrict__ Xp,    // [Tc*64][1024]
    const f16* __restrict__ Whr,   // [1024][KR]
    const f16* __restrict__ Whl,   // [4][1024][8]
    float* __restrict__ out,       // outputs [1024][64][256] fp32
    f16* __restrict__ hxs,         // [64][256] f16 state
    float* __restrict__ cxs,       // [64][256] f32 state
    float* __restrict__ hxout,     // d_out + 16777216
    float* __restrict__ cxout,     // d_out + 16777216 + 16384
    int t0, int t1) {
  extern __shared__ char smem[];
  f16* wlds = (f16*)smem;               // [4][1024][8] = 64KB
  f16* hxb = (f16*)(smem + 65536);      // [2][256] double-buffered hx

  int b = blockIdx.x;
  int h = threadIdx.x;

  // stage LDS weights (4096 uint4)
  {
    const uint4* src = (const uint4*)Whl;
    uint4* dst = (uint4*)smem;
#pragma unroll
    for (int i = 0; i < 16; ++i) dst[i * 256 + h] = src[i * 256 + h];
  }

  // load register weights: 4 cols x 28 uint4
  uint4 wr[4][28];
#pragma unroll
  for (int g = 0; g < 4; ++g) {
    const uint4* p = (const uint4*)(Whr + ((size_t)((g << 8) + h)) * KR);
#pragma unroll
    for (int c = 0; c < 28; ++c) wr[g][c] = p[c];
  }

  float cx;
  if (t0 == 0) {
    hxb[h] = (f16)0.0f;          // parity 0 (t0 always even)
    cx = 0.0f;
  } else {
    hxb[h] = hxs[b * 256 + h];
    cx = cxs[b * 256 + h];
  }

  const f16* xpb = Xp + (size_t)b * 1024 + h;
  f16 xc0 = xpb[0], xc1 = xpb[256], xc2 = xpb[512], xc3 = xpb[768];

  __syncthreads();

  float hv = 0.0f;
  for (int t = t0; t < t1; ++t) {
    float a0 = (float)xc0, a1 = (float)xc1, a2 = (float)xc2, a3 = (float)xc3;

    // prefetch next step's Xp (independent of recurrence)
    int tn = (t + 1 < t1) ? (t + 1 - t0) : (t - t0);
    const f16* xq = Xp + (size_t)tn * (BATCH * NCOL) + (size_t)b * 1024 + h;
    f16 xn0 = xq[0], xn1 = xq[256], xn2 = xq[512], xn3 = xq[768];

    const f16* hxc = hxb + ((t & 1) << 8);

    // K rows 0..223 from VGPR weights, hx broadcast from LDS
#pragma unroll
    for (int kc = 0; kc < 28; ++kc) {
      uint4 hh = *(const uint4*)(hxc + kc * 8);
      a0 = dot2(hh.x, wr[0][kc].x, a0); a0 = dot2(hh.y, wr[0][kc].y, a0);
      a0 = dot2(hh.z, wr[0][kc].z, a0); a0 = dot2(hh.w, wr[0][kc].w, a0);
      a1 = dot2(hh.x, wr[1][kc].x, a1); a1 = dot2(hh.y, wr[1][kc].y, a1);
      a1 = dot2(hh.z, wr[1][kc].z, a1); a1 = dot2(hh.w, wr[1][kc].w, a1);
      a2 = dot2(hh.x, wr[2][kc].x, a2); a2 = dot2(hh.y, wr[2][kc].y, a2);
      a2 = dot2(hh.z, wr[2][kc].z, a2); a2 = dot2(hh.w, wr[2][kc].w, a2);
      a3 = dot2(hh.x, wr[3][kc].x, a3); a3 = dot2(hh.y, wr[3][kc].y, a3);
      a3 = dot2(hh.z, wr[3][kc].z, a3); a3 = dot2(hh.w, wr[3][kc].w, a3);
    }
    // K rows 224..255 from LDS weights
#pragma unroll
    for (int c = 0; c < 4; ++c) {
      uint4 hh = *(const uint4*)(hxc + (28 + c) * 8);
      {
        uint4 ww = *(const uint4*)(wlds + ((size_t)(c << 10) + h) * 8);
        a0 = dot2(hh.x, ww.x, a0); a0 = dot2(hh.y, ww.y, a0);
        a0 = dot2(hh.z, ww.z, a0); a0 = dot2(hh.w, ww.w, a0);
      }
      {
        uint4 ww = *(const uint4*)(wlds + ((size_t)(c << 10) + 256 + h) * 8);
        a1 = dot2(hh.x, ww.x, a1); a1 = dot2(hh.y, ww.y, a1);
        a1 = dot2(hh.z, ww.z, a1); a1 = dot2(hh.w, ww.w, a1);
      }
      {
        uint4 ww = *(const uint4*)(wlds + ((size_t)(c << 10) + 512 + h) * 8);
        a2 = dot2(hh.x, ww.x, a2); a2 = dot2(hh.y, ww.y, a2);
        a2 = dot2(hh.z, ww.z, a2); a2 = dot2(hh.w, ww.w, a2);
      }
      {
        uint4 ww = *(const uint4*)(wlds + ((size_t)(c << 10) + 768 + h) * 8);
        a3 = dot2(hh.x, ww.x, a3); a3 = dot2(hh.y, ww.y, a3);
        a3 = dot2(hh.z, ww.z, a3); a3 = dot2(hh.w, ww.w, a3);
      }
    }

    float vf = fast_sigmoid(a0);
    float vi = fast_sigmoid(a1);
    float vg = fast_tanh(a2);
    float vo = fast_sigmoid(a3);
    cx = fmaf(vf, cx, vi * vg);
    hv = vo * fast_tanh(cx);

    out[((size_t)t * BATCH + b) * 256 + h] = hv;
    hxb[(((t + 1) & 1) << 8) + h] = (f16)hv;

    xc0 = xn0; xc1 = xn1; xc2 = xn2; xc3 = xn3;
    __syncthreads();
  }

  // persist state for next chunk
  hxs[b * 256 + h] = (f16)hv;
  cxs[b * 256 + h] = cx;
  if (t1 == SEQ) {
    hxout[b * 256 + h] = hv;
    cxout[b * 256 + h] = cx;
  }
}

extern "C" void kernel_launch(void* const* d_in, const int* in_sizes, int n_in,
                              void* d_out, int out_size, void* d_ws, size_t ws_size,
                              hipStream_t stream) {
  const float* X  = (const float*)d_in[0];
  const float* Wf = (const float*)d_in[1]; const float* bf_ = (const float*)d_in[2];
  const float* Wi = (const float*)d_in[3]; const float* bi_ = (const float*)d_in[4];
  const float* Wg = (const float*)d_in[5]; const float* bg_ = (const float*)d_in[6];
  const float* Wo = (const float*)d_in[7]; const float* bo_ = (const float*)d_in[8];
  float* out = (float*)d_out;

  char* ws = (char*)d_ws;
  f16*   Wxp   = (f16*)(ws + WXP_OFF);
  f16*   Whr   = (f16*)(ws + WHR_OFF);
  f16*   Whl   = (f16*)(ws + WHL_OFF);
  float* biasp = (float*)(ws + BIAS_OFF);
  f16*   hxs   = (f16*)(ws + HXS_OFF);
  float* cxs   = (float*)(ws + CXS_OFF);
  f16*   Xp    = (f16*)(ws + XP_OFF);

  // chunk size so Xp fits in workspace
  size_t avail = (ws_size > XP_OFF) ? (ws_size - XP_OFF) : 0;
  int Tc = SEQ;
  while (Tc > 2 && (size_t)Tc * BATCH * NCOL * 2 > avail) Tc >>= 1;

  qlstm_prep<<<2048, 256, 0, stream>>>(Wf, Wi, Wg, Wo, bf_, bi_, bg_, bo_,
                                       Wxp, Whr, Whl, biasp);

  // phase-2 needs 65 KB dynamic LDS (> 64 KB static limit)
  (void)hipFuncSetAttribute((const void*)qlstm_seq,
                            hipFuncAttributeMaxDynamicSharedMemorySize, 66560);

  float* hxout = out + (size_t)SEQ * BATCH * DH;
  float* cxout = hxout + BATCH * DH;

  for (int t0 = 0; t0 < SEQ; t0 += Tc) {
    dim3 g1(Tc * BATCH / 128, NCOL / 128);
    qlstm_xproj<<<g1, 256, 0, stream>>>(X + (size_t)t0 * BATCH * DIN, Wxp, biasp, Xp);
    qlstm_seq<<<BATCH, 256, 66560, stream>>>(Xp, Whr, Whl, out, hxs, cxs,
                                             hxout, cxout, t0, t0 + Tc);
  }
}

// Round 2
// 2816.598 us; speedup vs baseline: 2.1686x; 2.1686x over previous
//
#include <hip/hip_runtime.h>
#include <hip/hip_bf16.h>

// QLSTM: SEQ=1024, B=64, D_IN=256, D_H=256, fp32 in/out.
// Phase 1: Xp = x @ Wx + bias  (f16 MFMA GEMM, no sequential dep)
// Phase 2: 64 independent recurrences, 1 WG (256 thr) per batch element.
//   Wh rows 0..79   -> arch VGPRs (4 cols * 10 uint4 = 160 regs, under 256 cap)
//   Wh rows 80..103 -> LDS (48 KB)
//   Wh rows 104..255-> streamed from L2 each step (same data for all WGs)
// Round-1 lesson: 448-reg weight array spilled to scratch (72 GB HBM churn).

typedef _Float16 f16;
typedef _Float16 f16x2 __attribute__((ext_vector_type(2)));
typedef _Float16 f16x4 __attribute__((ext_vector_type(4)));
typedef _Float16 f16x8 __attribute__((ext_vector_type(8)));
typedef float f32x4 __attribute__((ext_vector_type(4)));

#define SEQ 1024
#define BATCH 64
#define DIN 256
#define DH 256
#define NCOL 1024
#define R1 80            // rows in VGPRs (10 chunks of 8)
#define R1C 10
#define R3 24            // rows in LDS (3 chunks)
#define RSC 19           // streamed chunks (152 rows)

// ---- ws layout (bytes) ----
#define WXP_OFF   0u                 // f16 [32][1024][8]
#define WHV_OFF   524288u            // f16 [1024][80]
#define WHL_OFF   688128u            // f16 [3][1024][8]
#define WHS_OFF   737280u            // f16 [19][1024][8]
#define BIAS_OFF  1048576u           // f32 [1024]
#define HXS_OFF   1052672u           // f16 [64][256]
#define CXS_OFF   1085440u           // f32 [64][256]
#define XP_OFF    1150976u           // f16 [Tc*64][1024]

__device__ __forceinline__ float dot2(unsigned int h, unsigned int w, float acc) {
#if __has_builtin(__builtin_amdgcn_fdot2)
  return __builtin_amdgcn_fdot2(__builtin_bit_cast(f16x2, h),
                                __builtin_bit_cast(f16x2, w), acc, false);
#else
  f16x2 a = __builtin_bit_cast(f16x2, h);
  f16x2 b = __builtin_bit_cast(f16x2, w);
  return acc + (float)a[0] * (float)b[0] + (float)a[1] * (float)b[1];
#endif
}

__device__ __forceinline__ void dot16(uint4 hh, const uint4& w0, const uint4& w1,
                                      const uint4& w2, const uint4& w3,
                                      float& a0, float& a1, float& a2, float& a3) {
  a0 = dot2(hh.x, w0.x, a0); a0 = dot2(hh.y, w0.y, a0);
  a0 = dot2(hh.z, w0.z, a0); a0 = dot2(hh.w, w0.w, a0);
  a1 = dot2(hh.x, w1.x, a1); a1 = dot2(hh.y, w1.y, a1);
  a1 = dot2(hh.z, w1.z, a1); a1 = dot2(hh.w, w1.w, a1);
  a2 = dot2(hh.x, w2.x, a2); a2 = dot2(hh.y, w2.y, a2);
  a2 = dot2(hh.z, w2.z, a2); a2 = dot2(hh.w, w2.w, a2);
  a3 = dot2(hh.x, w3.x, a3); a3 = dot2(hh.y, w3.y, a3);
  a3 = dot2(hh.z, w3.z, a3); a3 = dot2(hh.w, w3.w, a3);
}

__device__ __forceinline__ float fast_sigmoid(float x) {
  float e = __expf(-x);
  return __builtin_amdgcn_rcpf(1.0f + e);
}
__device__ __forceinline__ float fast_tanh(float x) {
  x = fminf(fmaxf(x, -15.0f), 15.0f);
  float e = __expf(2.0f * x);
  return (e - 1.0f) * __builtin_amdgcn_rcpf(e + 1.0f);
}

// ---------------- prep: convert / repack weights ----------------
__global__ void qlstm_prep(const float* __restrict__ Wf, const float* __restrict__ Wi,
                           const float* __restrict__ Wg, const float* __restrict__ Wo,
                           const float* __restrict__ bf_, const float* __restrict__ bi_,
                           const float* __restrict__ bg_, const float* __restrict__ bo_,
                           f16* __restrict__ Wxp, f16* __restrict__ WhV,
                           f16* __restrict__ WhL, f16* __restrict__ WhS,
                           float* __restrict__ biasp) {
  int tid = blockIdx.x * 256 + threadIdx.x;
  if (tid < 4 * 512 * 256) {
    int g = tid >> 17;
    int rem = tid & 131071;
    int k = rem >> 8, n = rem & 255;
    const float* W = (g == 0) ? Wf : (g == 1) ? Wi : (g == 2) ? Wg : Wo;
    float v = W[k * 256 + n];
    int j = (g << 8) + n;
    f16 hv = (f16)v;
    if (k < 256) {
      Wxp[((size_t)(k >> 3) * 1024 + j) * 8 + (k & 7)] = hv;
    } else {
      int kk = k - 256;
      if (kk < R1) {
        WhV[(size_t)j * R1 + kk] = hv;
      } else if (kk < R1 + R3) {
        int r = kk - R1;
        WhL[((size_t)(r >> 3) * 1024 + j) * 8 + (r & 7)] = hv;
      } else {
        int r = kk - (R1 + R3);
        WhS[((size_t)(r >> 3) * 1024 + j) * 8 + (r & 7)] = hv;
      }
    }
  }
  if (tid < 1024) {
    int g = tid >> 8, n = tid & 255;
    const float* bb = (g == 0) ? bf_ : (g == 1) ? bi_ : (g == 2) ? bg_ : bo_;
    biasp[tid] = bb[n];
  }
}

// ---------------- phase 1: Xp = x @ Wx + bias  (MFMA f16) ----------------
__global__ __launch_bounds__(256) void qlstm_xproj(
    const float* __restrict__ X, const f16* __restrict__ Wxp,
    const float* __restrict__ biasp, f16* __restrict__ Xp) {
  __shared__ f16 As[128][72];
  __shared__ f16 Bs[8 * 128 * 8];

  int tid = threadIdx.x;
  int tm = blockIdx.x, tn = blockIdx.y;
  int wave = tid >> 6, lane = tid & 63;
  int qm = (wave & 1) * 64, qn = (wave >> 1) * 64;
  int lm = lane & 15, lk = lane >> 4;

  f32x4 acc[4][4];
#pragma unroll
  for (int a = 0; a < 4; ++a)
#pragma unroll
    for (int b = 0; b < 4; ++b) acc[a][b] = (f32x4)0.0f;

  for (int k0 = 0; k0 < 256; k0 += 64) {
    {
      int r = tid >> 1, c0 = (tid & 1) * 32;
      const float4* src = (const float4*)(X + (size_t)(tm * 128 + r) * 256 + k0 + c0);
#pragma unroll
      for (int i = 0; i < 8; ++i) {
        float4 v = src[i];
        f16x4 pk = {(f16)v.x, (f16)v.y, (f16)v.z, (f16)v.w};
        *(f16x4*)&As[r][c0 + i * 4] = pk;
      }
    }
    {
#pragma unroll
      for (int it = 0; it < 4; ++it) {
        int idx = it * 256 + tid;
        int kgi = idx >> 7, n = idx & 127;
        ((uint4*)Bs)[idx] =
            *(const uint4*)(Wxp + (((size_t)(k0 >> 3) + kgi) * 1024 + tn * 128 + n) * 8);
      }
    }
    __syncthreads();
#pragma unroll
    for (int ks = 0; ks < 2; ++ks) {
      f16x8 af[4], bfr[4];
#pragma unroll
      for (int mi = 0; mi < 4; ++mi)
        af[mi] = *(const f16x8*)&As[qm + mi * 16 + lm][ks * 32 + lk * 8];
#pragma unroll
      for (int ni = 0; ni < 4; ++ni)
        bfr[ni] = *(const f16x8*)&Bs[(((ks * 4 + lk) * 128) + qn + ni * 16 + lm) * 8];
#pragma unroll
      for (int mi = 0; mi < 4; ++mi)
#pragma unroll
        for (int ni = 0; ni < 4; ++ni)
          acc[mi][ni] = __builtin_amdgcn_mfma_f32_16x16x32_f16(af[mi], bfr[ni],
                                                               acc[mi][ni], 0, 0, 0);
    }
    __syncthreads();
  }
  int m0 = tm * 128 + qm, j0 = tn * 128 + qn;
#pragma unroll
  for (int mi = 0; mi < 4; ++mi)
#pragma unroll
    for (int ni = 0; ni < 4; ++ni) {
      int j = j0 + ni * 16 + lm;
      float bv = biasp[j];
#pragma unroll
      for (int r = 0; r < 4; ++r) {
        int m = m0 + mi * 16 + lk * 4 + r;
        Xp[(size_t)m * 1024 + j] = (f16)(acc[mi][ni][r] + bv);
      }
    }
}

// ---------------- phase 2: sequential LSTM ----------------
__global__ __launch_bounds__(256, 1) void qlstm_seq(
    const f16* __restrict__ Xp, const f16* __restrict__ WhV,
    const f16* __restrict__ WhL, const f16* __restrict__ WhS,
    float* __restrict__ out, f16* __restrict__ hxs, float* __restrict__ cxs,
    float* __restrict__ hxout, float* __restrict__ cxout, int t0, int t1) {
  __shared__ __align__(16) f16 wlds[3 * 1024 * 8];   // 48 KB
  __shared__ __align__(16) f16 hxb[2 * 256];         // 1 KB

  int b = blockIdx.x;
  int h = threadIdx.x;

  // stage LDS weights (3072 uint4, coalesced)
  {
    const uint4* src = (const uint4*)WhL;
    uint4* dst = (uint4*)wlds;
#pragma unroll
    for (int i = 0; i < 12; ++i) dst[i * 256 + h] = src[i * 256 + h];
  }

  // register-resident weights: 4 cols x 10 uint4 = 160 VGPRs
  uint4 wr[4][R1C];
#pragma unroll
  for (int g = 0; g < 4; ++g) {
    const uint4* p = (const uint4*)(WhV + (size_t)((g << 8) + h) * R1);
#pragma unroll
    for (int c = 0; c < R1C; ++c) wr[g][c] = p[c];
  }

  float cx;
  if (t0 == 0) {
    hxb[h] = (f16)0.0f;
    cx = 0.0f;
  } else {
    hxb[h] = hxs[b * 256 + h];
    cx = cxs[b * 256 + h];
  }

  const f16* xpb = Xp + (size_t)b * 1024 + h;
  f16 xc0 = xpb[0], xc1 = xpb[256], xc2 = xpb[512], xc3 = xpb[768];

  const uint4* wsp = (const uint4*)WhS + h;   // stream base; +c*1024 + g*256
  const uint4* wl = (const uint4*)wlds;

  __syncthreads();

  float hv = 0.0f;
  for (int t = t0; t < t1; ++t) {
    float a0 = (float)xc0, a1 = (float)xc1, a2 = (float)xc2, a3 = (float)xc3;

    // prefetch next step's Xp
    int tnx = (t + 1 < t1) ? (t + 1 - t0) : (t - t0);
    const f16* xq = Xp + (size_t)tnx * (BATCH * NCOL) + (size_t)b * 1024 + h;
    f16 xn0 = xq[0], xn1 = xq[256], xn2 = xq[512], xn3 = xq[768];

    const uint4* hxc = (const uint4*)(hxb + ((t & 1) << 8));

    // depth-3 stream pipeline
    uint4 sb[3][4];
#pragma unroll
    for (int c = 0; c < 3; ++c)
#pragma unroll
      for (int g = 0; g < 4; ++g) sb[c][g] = wsp[c * 1024 + g * 256];

#pragma unroll
    for (int c = 0; c < RSC; ++c) {
      // consume streamed chunk c (hx rows 104+8c)
      {
        uint4 hh = hxc[13 + c];
        dot16(hh, sb[c % 3][0], sb[c % 3][1], sb[c % 3][2], sb[c % 3][3],
              a0, a1, a2, a3);
      }
      // refill same slot with chunk c+3
      if (c + 3 < RSC) {
#pragma unroll
        for (int g = 0; g < 4; ++g) sb[c % 3][g] = wsp[(c + 3) * 1024 + g * 256];
      }
      // interleave VGPR-resident chunks on even iterations (10 total)
      if ((c & 1) == 0) {
        int v = c >> 1;
        uint4 hh = hxc[v];
        dot16(hh, wr[0][v], wr[1][v], wr[2][v], wr[3][v], a0, a1, a2, a3);
      }
      // LDS-resident chunks at tail iterations
      if (c == 14 || c == 16 || c == 18) {
        int l = (c - 14) >> 1;
        uint4 hh = hxc[10 + l];
        uint4 q0 = wl[l * 1024 + h];
        uint4 q1 = wl[l * 1024 + 256 + h];
        uint4 q2 = wl[l * 1024 + 512 + h];
        uint4 q3 = wl[l * 1024 + 768 + h];
        dot16(hh, q0, q1, q2, q3, a0, a1, a2, a3);
      }
    }

    float vf = fast_sigmoid(a0);
    float vi = fast_sigmoid(a1);
    float vg = fast_tanh(a2);
    float vo = fast_sigmoid(a3);
    cx = fmaf(vf, cx, vi * vg);
    hv = vo * fast_tanh(cx);

    out[((size_t)t * BATCH + b) * 256 + h] = hv;
    hxb[(((t + 1) & 1) << 8) + h] = (f16)hv;

    xc0 = xn0; xc1 = xn1; xc2 = xn2; xc3 = xn3;
    __syncthreads();
  }

  hxs[b * 256 + h] = (f16)hv;
  cxs[b * 256 + h] = cx;
  if (t1 == SEQ) {
    hxout[b * 256 + h] = hv;
    cxout[b * 256 + h] = cx;
  }
}

extern "C" void kernel_launch(void* const* d_in, const int* in_sizes, int n_in,
                              void* d_out, int out_size, void* d_ws, size_t ws_size,
                              hipStream_t stream) {
  const float* X  = (const float*)d_in[0];
  const float* Wf = (const float*)d_in[1]; const float* bf_ = (const float*)d_in[2];
  const float* Wi = (const float*)d_in[3]; const float* bi_ = (const float*)d_in[4];
  const float* Wg = (const float*)d_in[5]; const float* bg_ = (const float*)d_in[6];
  const float* Wo = (const float*)d_in[7]; const float* bo_ = (const float*)d_in[8];
  float* out = (float*)d_out;

  char* ws = (char*)d_ws;
  f16*   Wxp   = (f16*)(ws + WXP_OFF);
  f16*   WhV   = (f16*)(ws + WHV_OFF);
  f16*   WhL   = (f16*)(ws + WHL_OFF);
  f16*   WhS   = (f16*)(ws + WHS_OFF);
  float* biasp = (float*)(ws + BIAS_OFF);
  f16*   hxs   = (f16*)(ws + HXS_OFF);
  float* cxs   = (float*)(ws + CXS_OFF);
  f16*   Xp    = (f16*)(ws + XP_OFF);

  size_t avail = (ws_size > XP_OFF) ? (ws_size - XP_OFF) : 0;
  int Tc = SEQ;
  while (Tc > 2 && (size_t)Tc * BATCH * NCOL * 2 > avail) Tc >>= 1;

  qlstm_prep<<<2048, 256, 0, stream>>>(Wf, Wi, Wg, Wo, bf_, bi_, bg_, bo_,
                                       Wxp, WhV, WhL, WhS, biasp);

  float* hxout = out + (size_t)SEQ * BATCH * DH;
  float* cxout = hxout + BATCH * DH;

  for (int t0 = 0; t0 < SEQ; t0 += Tc) {
    dim3 g1(Tc * BATCH / 128, NCOL / 128);
    qlstm_xproj<<<g1, 256, 0, stream>>>(X + (size_t)t0 * BATCH * DIN, Wxp, biasp, Xp);
    qlstm_seq<<<BATCH, 256, 0, stream>>>(Xp, WhV, WhL, WhS, out, hxs, cxs,
                                         hxout, cxout, t0, t0 + Tc);
  }
}

// Round 3
// 2059.549 us; speedup vs baseline: 2.9657x; 1.3676x over previous
//
#include <hip/hip_runtime.h>
#include <hip/hip_bf16.h>

// QLSTM: SEQ=1024, B=64, D_IN=256, D_H=256, fp32 in/out.
// Phase 1: Xp = x @ Wx + bias  (f16 MFMA GEMM, no sequential dep)
// Phase 2: 64 independent recurrences, 1 WG (512 thr, 8 waves) per batch.
//   Thread (p = tid>>8, h = tid&255) owns 2 gate-cols: p=0 -> {f,i}, p=1 -> {g,o}.
//   Wh rows 0..183  -> VGPRs (2 cols * 23 uint4 = 184 regs; 2 waves/SIMD uses the
//                     full 512 KB/CU file — round-2 L1-streaming wall removed)
//   Wh rows 184..255-> LDS (144 KB)
//   hx: one ds_read_b64/lane (lane l holds hx[4l..4l+4)), then v_readlane -> SGPR
//       feeding v_dot2_f32_f16 (keeps hx off the LDS pipe in the hot loop).
// Round-1 lesson: >256 regs/thread spills to scratch. Round-2 lesson: streaming
// weights through L1 costs 64 B/cyc/CU -> 4860 cyc/step; must be resident.

typedef _Float16 f16;
typedef _Float16 f16x2 __attribute__((ext_vector_type(2)));
typedef _Float16 f16x4 __attribute__((ext_vector_type(4)));
typedef _Float16 f16x8 __attribute__((ext_vector_type(8)));
typedef float f32x4 __attribute__((ext_vector_type(4)));

#define SEQ 1024
#define BATCH 64
#define DIN 256
#define DH 256
#define NCOL 1024
#define RV 184           // rows in VGPRs (23 chunks of 8)
#define RVC 23
#define RLC 9            // LDS chunks (72 rows)

// ---- ws layout (bytes) ----
#define WXP_OFF   0u                 // f16 [32][1024][8]
#define WHV_OFF   524288u            // f16 [1024 cols][184 rows]
#define WHL_OFF   901120u            // f16 [9][1024][8]
#define BIAS_OFF  1048576u           // f32 [1024]
#define HXS_OFF   1052672u           // f16 [64][256]
#define CXS_OFF   1085440u           // f32 [64][256]
#define XP_OFF    1150976u           // f16 [Tc*64][1024]

#define SEQ_LDS_BYTES 150528         // 147456 wts + 1024 hx + 2048 exch

__device__ __forceinline__ float dot2(unsigned int h, unsigned int w, float acc) {
#if __has_builtin(__builtin_amdgcn_fdot2)
  return __builtin_amdgcn_fdot2(__builtin_bit_cast(f16x2, h),
                                __builtin_bit_cast(f16x2, w), acc, false);
#else
  f16x2 a = __builtin_bit_cast(f16x2, h);
  f16x2 b = __builtin_bit_cast(f16x2, w);
  return acc + (float)a[0] * (float)b[0] + (float)a[1] * (float)b[1];
#endif
}

__device__ __forceinline__ float fast_sigmoid(float x) {
  float e = __expf(-x);
  return __builtin_amdgcn_rcpf(1.0f + e);
}
__device__ __forceinline__ float fast_tanh(float x) {
  x = fminf(fmaxf(x, -15.0f), 15.0f);
  float e = __expf(2.0f * x);
  return (e - 1.0f) * __builtin_amdgcn_rcpf(e + 1.0f);
}

// ---------------- prep: convert / repack weights ----------------
__global__ void qlstm_prep(const float* __restrict__ Wf, const float* __restrict__ Wi,
                           const float* __restrict__ Wg, const float* __restrict__ Wo,
                           const float* __restrict__ bf_, const float* __restrict__ bi_,
                           const float* __restrict__ bg_, const float* __restrict__ bo_,
                           f16* __restrict__ Wxp, f16* __restrict__ WhV,
                           f16* __restrict__ WhL, float* __restrict__ biasp) {
  int tid = blockIdx.x * 256 + threadIdx.x;
  if (tid < 4 * 512 * 256) {
    int g = tid >> 17;
    int rem = tid & 131071;
    int k = rem >> 8, n = rem & 255;
    const float* W = (g == 0) ? Wf : (g == 1) ? Wi : (g == 2) ? Wg : Wo;
    float v = W[k * 256 + n];
    int j = (g << 8) + n;
    f16 hv = (f16)v;
    if (k < 256) {
      Wxp[((size_t)(k >> 3) * 1024 + j) * 8 + (k & 7)] = hv;
    } else {
      int kk = k - 256;
      if (kk < RV) {
        WhV[(size_t)j * RV + kk] = hv;
      } else {
        int r = kk - RV;
        WhL[((size_t)(r >> 3) * 1024 + j) * 8 + (r & 7)] = hv;
      }
    }
  }
  if (tid < 1024) {
    int g = tid >> 8, n = tid & 255;
    const float* bb = (g == 0) ? bf_ : (g == 1) ? bi_ : (g == 2) ? bg_ : bo_;
    biasp[tid] = bb[n];
  }
}

// ---------------- phase 1: Xp = x @ Wx + bias  (MFMA f16) ----------------
__global__ __launch_bounds__(256) void qlstm_xproj(
    const float* __restrict__ X, const f16* __restrict__ Wxp,
    const float* __restrict__ biasp, f16* __restrict__ Xp) {
  __shared__ f16 As[128][72];
  __shared__ f16 Bs[8 * 128 * 8];

  int tid = threadIdx.x;
  int tm = blockIdx.x, tn = blockIdx.y;
  int wave = tid >> 6, lane = tid & 63;
  int qm = (wave & 1) * 64, qn = (wave >> 1) * 64;
  int lm = lane & 15, lk = lane >> 4;

  f32x4 acc[4][4];
#pragma unroll
  for (int a = 0; a < 4; ++a)
#pragma unroll
    for (int b = 0; b < 4; ++b) acc[a][b] = (f32x4)0.0f;

  for (int k0 = 0; k0 < 256; k0 += 64) {
    {
      int r = tid >> 1, c0 = (tid & 1) * 32;
      const float4* src = (const float4*)(X + (size_t)(tm * 128 + r) * 256 + k0 + c0);
#pragma unroll
      for (int i = 0; i < 8; ++i) {
        float4 v = src[i];
        f16x4 pk = {(f16)v.x, (f16)v.y, (f16)v.z, (f16)v.w};
        *(f16x4*)&As[r][c0 + i * 4] = pk;
      }
    }
    {
#pragma unroll
      for (int it = 0; it < 4; ++it) {
        int idx = it * 256 + tid;
        int kgi = idx >> 7, n = idx & 127;
        ((uint4*)Bs)[idx] =
            *(const uint4*)(Wxp + (((size_t)(k0 >> 3) + kgi) * 1024 + tn * 128 + n) * 8);
      }
    }
    __syncthreads();
#pragma unroll
    for (int ks = 0; ks < 2; ++ks) {
      f16x8 af[4], bfr[4];
#pragma unroll
      for (int mi = 0; mi < 4; ++mi)
        af[mi] = *(const f16x8*)&As[qm + mi * 16 + lm][ks * 32 + lk * 8];
#pragma unroll
      for (int ni = 0; ni < 4; ++ni)
        bfr[ni] = *(const f16x8*)&Bs[(((ks * 4 + lk) * 128) + qn + ni * 16 + lm) * 8];
#pragma unroll
      for (int mi = 0; mi < 4; ++mi)
#pragma unroll
        for (int ni = 0; ni < 4; ++ni)
          acc[mi][ni] = __builtin_amdgcn_mfma_f32_16x16x32_f16(af[mi], bfr[ni],
                                                               acc[mi][ni], 0, 0, 0);
    }
    __syncthreads();
  }
  int m0 = tm * 128 + qm, j0 = tn * 128 + qn;
#pragma unroll
  for (int mi = 0; mi < 4; ++mi)
#pragma unroll
    for (int ni = 0; ni < 4; ++ni) {
      int j = j0 + ni * 16 + lm;
      float bv = biasp[j];
#pragma unroll
      for (int r = 0; r < 4; ++r) {
        int m = m0 + mi * 16 + lk * 4 + r;
        Xp[(size_t)m * 1024 + j] = (f16)(acc[mi][ni][r] + bv);
      }
    }
}

// ---------------- phase 2: sequential LSTM ----------------
__global__ __launch_bounds__(512, 2) void qlstm_seq(
    const f16* __restrict__ Xp, const f16* __restrict__ WhV,
    const f16* __restrict__ WhL,
    float* __restrict__ out, f16* __restrict__ hxs, float* __restrict__ cxs,
    float* __restrict__ hxout, float* __restrict__ cxout, int t0, int t1) {
  extern __shared__ char smem[];
  f16* wlds = (f16*)smem;                    // 147456 B: [9][1024][8]
  f16* hxb = (f16*)(smem + 147456);          // [2][256]
  float2* exch = (float2*)(smem + 148480);   // [256]

  int tid = threadIdx.x;
  int p = tid >> 8, h = tid & 255;
  int lane = tid & 63;
  int b = blockIdx.x;
  int j0 = p * 512 + h;          // p=0: f-gate col; p=1: g-gate col
  int j1 = j0 + 256;             // p=0: i-gate col; p=1: o-gate col

  // stage LDS weights (9216 uint4 over 512 threads)
  {
    const uint4* src = (const uint4*)WhL;
    uint4* dst = (uint4*)wlds;
#pragma unroll
    for (int i = 0; i < 18; ++i) dst[i * 512 + tid] = src[i * 512 + tid];
  }

  // VGPR-resident weights: 2 cols x 23 uint4 = 184 regs
  uint4 wr0[RVC], wr1[RVC];
  {
    const uint4* q0 = (const uint4*)WhV + (size_t)j0 * RVC;
    const uint4* q1 = (const uint4*)WhV + (size_t)j1 * RVC;
#pragma unroll
    for (int c = 0; c < RVC; ++c) { wr0[c] = q0[c]; wr1[c] = q1[c]; }
  }

  float cx = 0.0f;
  if (p == 0) {
    if (t0 == 0) {
      hxb[h] = (f16)0.0f;
    } else {
      hxb[h] = hxs[b * 256 + h];
      cx = cxs[b * 256 + h];
    }
  }

  const f16* xpb = Xp + (size_t)b * 1024;
  f16 xa = xpb[j0], xb_ = xpb[j1];

  __syncthreads();

  float hv = 0.0f;
  for (int t = t0; t < t1; ++t) {
    int par = t & 1;
    // whole hx into the wave: lane l holds hx[4l..4l+4)
    uint2 hl = *(const uint2*)(hxb + par * 256 + lane * 4);

    float a0 = (float)xa, a1 = (float)xb_;

    // prefetch next step's Xp (independent of recurrence)
    int tnx = (t + 1 < t1) ? (t + 1 - t0) : (t - t0);
    const f16* xq = Xp + (size_t)tnx * (BATCH * NCOL) + (size_t)b * 1024;
    f16 xna = xq[j0], xnb = xq[j1];

    // rows 0..183 from VGPR weights; hx via readlane -> SGPR operand of v_dot2
#pragma unroll
    for (int c = 0; c < RVC; ++c) {
      unsigned s0 = (unsigned)__builtin_amdgcn_readlane((int)hl.x, 2 * c);
      unsigned s1 = (unsigned)__builtin_amdgcn_readlane((int)hl.y, 2 * c);
      unsigned s2 = (unsigned)__builtin_amdgcn_readlane((int)hl.x, 2 * c + 1);
      unsigned s3 = (unsigned)__builtin_amdgcn_readlane((int)hl.y, 2 * c + 1);
      a0 = dot2(s0, wr0[c].x, a0); a0 = dot2(s1, wr0[c].y, a0);
      a0 = dot2(s2, wr0[c].z, a0); a0 = dot2(s3, wr0[c].w, a0);
      a1 = dot2(s0, wr1[c].x, a1); a1 = dot2(s1, wr1[c].y, a1);
      a1 = dot2(s2, wr1[c].z, a1); a1 = dot2(s3, wr1[c].w, a1);
    }
    // rows 184..255 from LDS
#pragma unroll
    for (int c = 0; c < RLC; ++c) {
      int cc = RVC + c;
      unsigned s0 = (unsigned)__builtin_amdgcn_readlane((int)hl.x, 2 * cc);
      unsigned s1 = (unsigned)__builtin_amdgcn_readlane((int)hl.y, 2 * cc);
      unsigned s2 = (unsigned)__builtin_amdgcn_readlane((int)hl.x, 2 * cc + 1);
      unsigned s3 = (unsigned)__builtin_amdgcn_readlane((int)hl.y, 2 * cc + 1);
      uint4 w0 = ((const uint4*)wlds)[(size_t)c * 1024 + j0];
      uint4 w1 = ((const uint4*)wlds)[(size_t)c * 1024 + j1];
      a0 = dot2(s0, w0.x, a0); a0 = dot2(s1, w0.y, a0);
      a0 = dot2(s2, w0.z, a0); a0 = dot2(s3, w0.w, a0);
      a1 = dot2(s0, w1.x, a1); a1 = dot2(s1, w1.y, a1);
      a1 = dot2(s2, w1.z, a1); a1 = dot2(s3, w1.w, a1);
    }

    if (p == 1) exch[h] = make_float2(a0, a1);   // (g, o) pre-activations
    __syncthreads();
    if (p == 0) {
      float2 go = exch[h];
      float vf = fast_sigmoid(a0);
      float vi = fast_sigmoid(a1);
      float vg = fast_tanh(go.x);
      float vo = fast_sigmoid(go.y);
      cx = fmaf(vf, cx, vi * vg);
      hv = vo * fast_tanh(cx);
      out[((size_t)t * BATCH + b) * 256 + h] = hv;
      hxb[(par ^ 1) * 256 + h] = (f16)hv;
    }
    __syncthreads();

    xa = xna; xb_ = xnb;
  }

  if (p == 0) {
    hxs[b * 256 + h] = (f16)hv;
    cxs[b * 256 + h] = cx;
    if (t1 == SEQ) {
      hxout[b * 256 + h] = hv;
      cxout[b * 256 + h] = cx;
    }
  }
}

extern "C" void kernel_launch(void* const* d_in, const int* in_sizes, int n_in,
                              void* d_out, int out_size, void* d_ws, size_t ws_size,
                              hipStream_t stream) {
  const float* X  = (const float*)d_in[0];
  const float* Wf = (const float*)d_in[1]; const float* bf_ = (const float*)d_in[2];
  const float* Wi = (const float*)d_in[3]; const float* bi_ = (const float*)d_in[4];
  const float* Wg = (const float*)d_in[5]; const float* bg_ = (const float*)d_in[6];
  const float* Wo = (const float*)d_in[7]; const float* bo_ = (const float*)d_in[8];
  float* out = (float*)d_out;

  char* ws = (char*)d_ws;
  f16*   Wxp   = (f16*)(ws + WXP_OFF);
  f16*   WhV   = (f16*)(ws + WHV_OFF);
  f16*   WhL   = (f16*)(ws + WHL_OFF);
  float* biasp = (float*)(ws + BIAS_OFF);
  f16*   hxs   = (f16*)(ws + HXS_OFF);
  float* cxs   = (float*)(ws + CXS_OFF);
  f16*   Xp    = (f16*)(ws + XP_OFF);

  size_t avail = (ws_size > XP_OFF) ? (ws_size - XP_OFF) : 0;
  int Tc = SEQ;
  while (Tc > 2 && (size_t)Tc * BATCH * NCOL * 2 > avail) Tc >>= 1;

  qlstm_prep<<<2048, 256, 0, stream>>>(Wf, Wi, Wg, Wo, bf_, bi_, bg_, bo_,
                                       Wxp, WhV, WhL, biasp);

  (void)hipFuncSetAttribute((const void*)qlstm_seq,
                            hipFuncAttributeMaxDynamicSharedMemorySize,
                            SEQ_LDS_BYTES);

  float* hxout = out + (size_t)SEQ * BATCH * DH;
  float* cxout = hxout + BATCH * DH;

  for (int t0 = 0; t0 < SEQ; t0 += Tc) {
    dim3 g1(Tc * BATCH / 128, NCOL / 128);
    qlstm_xproj<<<g1, 256, 0, stream>>>(X + (size_t)t0 * BATCH * DIN, Wxp, biasp, Xp);
    qlstm_seq<<<BATCH, 512, SEQ_LDS_BYTES, stream>>>(Xp, WhV, WhL, out, hxs, cxs,
                                                     hxout, cxout, t0, t0 + Tc);
  }
}